// Round 4
// baseline (440.434 us; speedup 1.0000x reference)
//
#include <hip/hip_runtime.h>

typedef unsigned short u16;
typedef unsigned int u32;
typedef __attribute__((ext_vector_type(8))) __bf16 bf16x8;
typedef __attribute__((ext_vector_type(4))) float f32x4;
typedef __attribute__((ext_vector_type(8))) unsigned short u16x8;
typedef __attribute__((ext_vector_type(4))) unsigned short u16x4;
typedef __attribute__((ext_vector_type(4))) unsigned int u32x4;

#define GLL(gp, lp) __builtin_amdgcn_global_load_lds((const __attribute__((address_space(1))) void*)(gp), (__attribute__((address_space(3))) void*)(lp), 16, 0, 0)

__device__ __forceinline__ u16 f2bf(float f) {
  u32 u = __float_as_uint(f);
  u += 0x7FFFu + ((u >> 16) & 1u);   // RNE; no NaNs in this pipeline
  return (u16)(u >> 16);
}
__device__ __forceinline__ float bf2f(u16 u) { return __uint_as_float(((u32)u) << 16); }
__device__ __forceinline__ u32 cvtpk(float lo, float hi) {  // D[15:0]=bf16(lo), D[31:16]=bf16(hi)
  u32 r;
  asm("v_cvt_pk_bf16_f32 %0, %1, %2" : "=v"(r) : "v"(lo), "v"(hi));
  return r;
}
__device__ __forceinline__ float qz(float v) {  // MASE integer_quantizer fwd, width=8 frac=4
  float r = rintf(v * 16.0f);
  r = fminf(127.0f, fmaxf(-128.0f, r));
  return r * 0.0625f;
}
__device__ __forceinline__ f32x4 mfma16(bf16x8 a, bf16x8 b, f32x4 c) {
  return __builtin_amdgcn_mfma_f32_16x16x32_bf16(a, b, c, 0, 0, 0);
}

// ---------------- quantize x, w_qkv, w_out -> bf16 (exact representations) -------------
// w_qkv rows are PERMUTED on store: src row h*192+d*3+comp -> dst row comp*512+h*64+d.
__global__ __launch_bounds__(256) void k_quant(const float* __restrict__ x,
                                               const float* __restrict__ wqkv,
                                               const float* __restrict__ wout,
                                               u16* __restrict__ xq,
                                               u16* __restrict__ wq,
                                               u16* __restrict__ wo) {
  const int X4 = 4194304;   // 4*8192*512 /4
  const int W4 = 196608;    // 1536*512 /4
  const int O4 = 65536;     // 512*512 /4
  int stride = gridDim.x * blockDim.x;
  for (int i = blockIdx.x * blockDim.x + threadIdx.x; i < X4 + W4 + O4; i += stride) {
    const float4* s; u16* d; int jl, jd;
    if (i < X4) {
      s = (const float4*)x; d = xq; jl = i; jd = i;
    } else if (i < X4 + W4) {
      s = (const float4*)wqkv; d = wq;
      jl = i - X4;
      int rs = jl >> 7;            // source row (128 float4 per 512-elem row)
      int jc = jl & 127;
      int h = rs / 192;
      int rem = rs - h * 192;
      int dd = rem / 3;
      int comp = rem - dd * 3;
      jd = (comp * 512 + h * 64 + dd) * 128 + jc;
    } else {
      s = (const float4*)wout; d = wo; jl = i - X4 - W4; jd = jl;
    }
    float4 v = s[jl];
    u16x4 o;
    o.x = f2bf(qz(v.x)); o.y = f2bf(qz(v.y)); o.z = f2bf(qz(v.z)); o.w = f2bf(qz(v.w));
    *(u16x4*)(d + (size_t)jd * 4) = o;
  }
}

// ---------------- rel_k = positions @ w_rel.T  -> bf16 [8][256][64];  pbR[h][256] ------
__global__ __launch_bounds__(128) void k_relk(const float* __restrict__ w_rel,
                                              const float* __restrict__ pb,   // [512]
                                              u16* __restrict__ relk,         // [8][256][64]
                                              float* __restrict__ pbR) {      // [8][256]
  int r = blockIdx.x;        // 0..255 (position index; d = r-127)
  int cseg = blockIdx.y;     // 0..3
  int tid = threadIdx.x;     // 0..127
  int c = cseg * 128 + tid;  // output channel 0..511: h = c>>6, d = c&63
  if (r == 255) {            // padding row: zero (read by MFMA A-frags, never selected)
    relk[((size_t)(c >> 6) * 256 + 255) * 64 + (c & 63)] = 0;
    if ((tid & 63) == 0) pbR[(c >> 6) * 256 + 255] = 0.f;
    return;
  }
  __shared__ float pos[512];
  float dd = (float)(r - 127);
  float ad = fabsf(dd);
  float sg = (dd > 0.f) ? 1.f : ((dd < 0.f) ? -1.f : 0.f);
  for (int f = tid; f < 512; f += 128) {
    int base = f & 255;
    float feat;
    if (base < 128) {  // exponential features: half_life = 2^linspace(3, 7, 128)
      float hl = exp2f(3.0f + (float)base * (4.0f / 127.0f));
      feat = expf((-0.6931471805599453f / hl) * ad);
    } else {           // central-mask features: 2^(j+1)-1 > |d|  (2^128 -> inf, matches ref)
      float cw = exp2f((float)(base - 128 + 1)) - 1.0f;
      feat = (cw > ad) ? 1.0f : 0.0f;
    }
    if (f >= 256) feat *= sg;
    pos[f] = feat;
  }
  __syncthreads();
  const float4* wr4 = (const float4*)(w_rel + (size_t)c * 512);
  float acc = 0.f;
  #pragma unroll 4
  for (int f4 = 0; f4 < 128; f4++) {
    float4 w4 = wr4[f4];
    int f = f4 * 4;
    acc += pos[f] * w4.x + pos[f + 1] * w4.y + pos[f + 2] * w4.z + pos[f + 3] * w4.w;
  }
  relk[((size_t)(c >> 6) * 256 + r) * 64 + (c & 63)] = f2bf(acc);
  float contrib = acc * pb[c];
  #pragma unroll
  for (int off = 1; off < 64; off <<= 1) contrib += __shfl_xor(contrib, off, 64);
  if ((tid & 63) == 0) pbR[(c >> 6) * 256 + r] = contrib;
}

// ---------------- QKV GEMM: [32768,512]bf16 @ [1536,512]bf16^T(permuted rows) ----------
__global__ __launch_bounds__(256) void k_gemm_qkv(const u16* __restrict__ Aq,
                                                  const u16* __restrict__ Bq,
                                                  u16* __restrict__ Qo,
                                                  u16* __restrict__ Ko,
                                                  u16* __restrict__ Vo) {
  __shared__ u16 As[128 * 32];
  __shared__ u16 Bs[128 * 32];
  int tid = threadIdx.x;
  int bid = blockIdx.x;
  int swz = (bid & 7) * (gridDim.x >> 3) + (bid >> 3);   // XCD swizzle (3072 % 8 == 0)
  int m0 = (swz / 12) * 128, n0 = (swz % 12) * 128;
  int wid = tid >> 6, lane = tid & 63, g = lane >> 4, r16 = lane & 15;
  int wm = wid >> 1, wn = wid & 1;
  f32x4 acc[4][4];
  #pragma unroll
  for (int i = 0; i < 4; i++)
    #pragma unroll
    for (int j = 0; j < 4; j++) acc[i][j] = (f32x4){0.f, 0.f, 0.f, 0.f};
  const u16* Ab = Aq + (size_t)m0 * 512;
  const u16* Bb = Bq + (size_t)n0 * 512;
  char* AsB = (char*)As + wid * 1024;
  char* BsB = (char*)Bs + wid * 1024;
  int srow = tid >> 2;
  int scol = ((tid & 3) ^ ((tid >> 3) & 3)) * 8;   // pre-swizzled source chunk
  int gs = (g ^ ((r16 >> 1) & 3)) * 8;             // swizzled read chunk
  for (int k0 = 0; k0 < 512; k0 += 32) {
    __syncthreads();
    GLL(Ab + (size_t)srow * 512 + k0 + scol, AsB);
    GLL(Ab + (size_t)(srow + 64) * 512 + k0 + scol, AsB + 4096);
    GLL(Bb + (size_t)srow * 512 + k0 + scol, BsB);
    GLL(Bb + (size_t)(srow + 64) * 512 + k0 + scol, BsB + 4096);
    __syncthreads();
    bf16x8 a[4], b[4];
    #pragma unroll
    for (int mt = 0; mt < 4; mt++)
      a[mt] = *(const bf16x8*)(As + (wm * 64 + mt * 16 + r16) * 32 + gs);
    #pragma unroll
    for (int nt = 0; nt < 4; nt++)
      b[nt] = *(const bf16x8*)(Bs + (wn * 64 + nt * 16 + r16) * 32 + gs);
    #pragma unroll
    for (int mt = 0; mt < 4; mt++)
      #pragma unroll
      for (int nt = 0; nt < 4; nt++) acc[mt][nt] = mfma16(a[mt], b[nt], acc[mt][nt]);
  }
  // epilogue: col -> (comp | h*64+d); store [b][h][n][64] bf16, 32B-coalesced runs
  #pragma unroll
  for (int nt = 0; nt < 4; nt++) {
    int colc = n0 + wn * 64 + nt * 16 + r16;
    int comp = colc >> 9;
    int hd = colc & 511;
    u16* dst = (comp == 0) ? Qo : (comp == 1 ? Ko : Vo);
    u16* dstp = dst + (size_t)(hd >> 6) * 524288 + (hd & 63);
    #pragma unroll
    for (int mt = 0; mt < 4; mt++) {
      int mbase = m0 + wm * 64 + mt * 16 + 4 * g;
      #pragma unroll
      for (int rr = 0; rr < 4; rr++) {
        int m = mbase + rr;
        int bb = m >> 13, nn = m & 8191;
        dstp[(size_t)bb * 4194304 + (size_t)nn * 64] = f2bf(acc[mt][nt][rr]);
      }
    }
  }
}

// ---------------- windowed attention (swapped-operand, Pst-free) -----------------------
// S^T layout: lane(g,r16) holds S[q=s*16+r16][k=kt*16+4g+rr]; softmax per-lane + 2 shfl;
// P redistributed to PV B-frags via in-register shuffles (no LDS P buffer).
__device__ __forceinline__ f32x4 rel_tile(const u16* __restrict__ Rh,
                                          const float* __restrict__ pbRh,
                                          bf16x8 qb0, bf16x8 qb1,
                                          int ct, int r16, int g) {
  const u16* rp = Rh + ((ct << 4) + r16) * 64 + (g << 3);
  bf16x8 rb0 = *(const bf16x8*)rp;
  bf16x8 rb1 = *(const bf16x8*)(rp + 32);
  f32x4 c = {0.f, 0.f, 0.f, 0.f};
  c = mfma16(rb0, qb0, c);
  c = mfma16(rb1, qb1, c);
  f32x4 pv = *(const f32x4*)(pbRh + (ct << 4) + (g << 2));
  c[0] += pv[0]; c[1] += pv[1]; c[2] += pv[2]; c[3] += pv[3];
  return c;
}

__global__ __launch_bounds__(512, 8) void k_attn(const u16* __restrict__ Q,
                                                 const u16* __restrict__ K,
                                                 const u16* __restrict__ V,
                                                 const u16* __restrict__ relk,
                                                 const float* __restrict__ pbR,
                                                 const float* __restrict__ cb,   // [512]
                                                 u16* __restrict__ attout) {
  int bid = blockIdx.x;            // 2048 = 4*8*64
  int bb = bid >> 9;
  int h = (bid >> 6) & 7;
  int w = bid & 63;
  int tid = threadIdx.x;
  int s = tid >> 6;                // wave id == q-stripe (16 rows)
  int lane = tid & 63, g = lane >> 4, r16 = lane & 15;
  const int n0 = w * 128;
  const u16* Qh = Q + ((size_t)(bb * 8 + h) * 8192 + n0) * 64;
  const u16* Kh = K + ((size_t)(bb * 8 + h) * 8192 + n0) * 64;
  const u16* Vh = V + ((size_t)(bb * 8 + h) * 8192 + n0) * 64;
  const u16* Rh = relk + (size_t)h * 256 * 64;
  const float* pbRh = pbR + h * 256;

  __shared__ u16 VT[64 * 128];      // V^T: key-chunk XOR-swizzled: chunk ^= (dv^(dv>>3))&7
  __shared__ float cbK[128];        // content-bias dot key

  // --- stage V transposed: 512 threads, each packs a key-PAIR for 8 dv (u32 writes, ~2-way)
  {
    int r2 = tid >> 3;               // key pair index 0..63 -> keys 2r2, 2r2+1
    int c0 = (tid & 7) << 3;         // dv base
    const u16* src = Vh + r2 * 128 + c0;
    u16x8 v0 = *(const u16x8*)src;
    u16x8 v1 = *(const u16x8*)(src + 64);
    int kc = r2 >> 2;                // key chunk (8 keys)
    int pos = (r2 & 3) << 1;         // position of key pair within chunk
    #pragma unroll
    for (int j = 0; j < 8; j++) {
      int dv = c0 + j;
      int swzv = (dv ^ (dv >> 3)) & 7;
      u32 wv = (u32)v0[j] | ((u32)v1[j] << 16);
      *(u32*)(VT + dv * 128 + ((kc ^ swzv) << 3) + pos) = wv;
    }
  }
  // --- cbK[k] = sum_d cb[h][d] * K[k][d] (f32; folds rel_content_bias exactly)
  if (tid < 128) {
    const u16x8* kr8 = (const u16x8*)(Kh + tid * 64);
    const float* cbh = cb + h * 64;
    float a = 0.f;
    #pragma unroll
    for (int d8 = 0; d8 < 8; d8++) {
      u16x8 kv = kr8[d8];
      #pragma unroll
      for (int j = 0; j < 8; j++) a += cbh[d8 * 8 + j] * bf2f(kv[j]);
    }
    cbK[tid] = a;
  }

  // --- Q fragments (B-operand: col = q = s*16 + r16)
  const u16* qptr = Qh + ((s << 4) + r16) * 64 + (g << 3);
  bf16x8 qb0 = *(const bf16x8*)qptr;
  bf16x8 qb1 = *(const bf16x8*)(qptr + 32);

  // --- content scores S[q][k] (swapped): sc[kt][rr] = S[q=r16][k=kt*16+4g+rr]
  f32x4 sc[8];
  #pragma unroll
  for (int kt = 0; kt < 8; kt++) {
    const u16* kp = Kh + ((kt << 4) + r16) * 64 + (g << 3);
    bf16x8 kf0 = *(const bf16x8*)kp;
    bf16x8 kf1 = *(const bf16x8*)(kp + 32);
    f32x4 c = {0.f, 0.f, 0.f, 0.f};
    c = mfma16(kf0, qb0, c);
    sc[kt] = mfma16(kf1, qb1, c);
  }

  // --- rel band + shift-gather. rl tile t holds RL[q=r16][c=ct*16+4g+rr], ct=7-s+t.
  // pos[q][k] = RL[q][127+k-q]: loc = 15+4g+rr-r16; tile kt (loc<16) or kt+1; cl=loc&15.
  int a0 = (3 - r16) & 3;            // per-lane register rotation amount
  bool rb0s = (a0 & 1) != 0, rb1s = (a0 & 2) != 0;
  float rotA[4], rotB[4];
  {
    f32x4 rl = rel_tile(Rh, pbRh, qb0, qb1, 7 - s, r16, g);
    float s1[4];
    #pragma unroll
    for (int i = 0; i < 4; i++) s1[i] = rb0s ? rl[(i + 1) & 3] : rl[i];
    #pragma unroll
    for (int i = 0; i < 4; i++) rotA[i] = rb1s ? s1[(i + 2) & 3] : s1[i];
  }
  // per-rr gather constants (independent of kt)
  int srcl[4]; bool hisel[4];
  #pragma unroll
  for (int rr = 0; rr < 4; rr++) {
    int loc = 15 + 4 * g + rr - r16;
    srcl[rr] = (((loc & 15) >> 2) << 4) | r16;
    hisel[rr] = loc >= 16;
  }

  __syncthreads();   // VT + cbK ready (also fences before cbK reads below)

  #pragma unroll
  for (int kt = 0; kt < 8; kt++) {
    f32x4 rl = rel_tile(Rh, pbRh, qb0, qb1, 8 - s + kt, r16, g);
    float s1[4];
    #pragma unroll
    for (int i = 0; i < 4; i++) s1[i] = rb0s ? rl[(i + 1) & 3] : rl[i];
    #pragma unroll
    for (int i = 0; i < 4; i++) rotB[i] = rb1s ? s1[(i + 2) & 3] : s1[i];
    f32x4 cbv = *(const f32x4*)(&cbK[(kt << 4) + (g << 2)]);
    #pragma unroll
    for (int rr = 0; rr < 4; rr++) {
      float vlo = __shfl(rotA[rr], srcl[rr], 64);
      float vhi = __shfl(rotB[rr], srcl[rr], 64);
      float posv = hisel[rr] ? vhi : vlo;
      sc[kt][rr] = (sc[kt][rr] + cbv[rr]) * 0.125f + posv;
    }
    #pragma unroll
    for (int i = 0; i < 4; i++) rotA[i] = rotB[i];
  }

  // --- softmax over k: per-lane 32 values + 2-step cross-lane (xor 16, 32)
  float mx = sc[0][0];
  #pragma unroll
  for (int kt = 0; kt < 8; kt++)
    #pragma unroll
    for (int rr = 0; rr < 4; rr++) mx = fmaxf(mx, sc[kt][rr]);
  mx = fmaxf(mx, __shfl_xor(mx, 16, 64));
  mx = fmaxf(mx, __shfl_xor(mx, 32, 64));
  float sum = 0.f;
  #pragma unroll
  for (int kt = 0; kt < 8; kt++)
    #pragma unroll
    for (int rr = 0; rr < 4; rr++) {
      float p = expf(sc[kt][rr] - mx);
      sc[kt][rr] = p;
      sum += p;
    }
  sum += __shfl_xor(sum, 16, 64);
  sum += __shfl_xor(sum, 32, 64);
  float inv = 1.0f / sum;

  // --- pack P to bf16 pairs: pk[kt][0]=(rr0,rr1), pk[kt][1]=(rr2,rr3)
  u32 pkb[8][2];
  #pragma unroll
  for (int kt = 0; kt < 8; kt++) {
    pkb[kt][0] = cvtpk(sc[kt][0], sc[kt][1]);
    pkb[kt][1] = cvtpk(sc[kt][2], sc[kt][3]);
  }

  // --- PV: O^T[dv][q] — B-frag built via 4-lane-group shuffles (static reg indices)
  f32x4 o[4];
  #pragma unroll
  for (int dvt = 0; dvt < 4; dvt++) o[dvt] = (f32x4){0.f, 0.f, 0.f, 0.f};
  int L0 = ((g & 1) << 5) | r16;
  int L1 = L0 + 16;
  bool ghi = g >= 2;
  #pragma unroll
  for (int ks = 0; ks < 4; ks++) {
    int e = 2 * ks;
    u32 w0a = __shfl((int)pkb[e][0], L0, 64), w0b = __shfl((int)pkb[e + 1][0], L0, 64);
    u32 w1a = __shfl((int)pkb[e][1], L0, 64), w1b = __shfl((int)pkb[e + 1][1], L0, 64);
    u32 w2a = __shfl((int)pkb[e][0], L1, 64), w2b = __shfl((int)pkb[e + 1][0], L1, 64);
    u32 w3a = __shfl((int)pkb[e][1], L1, 64), w3b = __shfl((int)pkb[e + 1][1], L1, 64);
    u32x4 wv;
    wv.x = ghi ? w0b : w0a;
    wv.y = ghi ? w1b : w1a;
    wv.z = ghi ? w2b : w2a;
    wv.w = ghi ? w3b : w3a;
    bf16x8 pf = __builtin_bit_cast(bf16x8, wv);
    #pragma unroll
    for (int dvt = 0; dvt < 4; dvt++) {
      int dv = (dvt << 4) | r16;
      int swzv = (dv ^ (dv >> 3)) & 7;
      bf16x8 vf = *(const bf16x8*)(VT + dv * 128 + (((ks * 4 + g) ^ swzv) << 3));
      o[dvt] = mfma16(vf, pf, o[dvt]);
    }
  }

  // --- epilogue: lane holds O[dv=dvt*16+4g+rr][q=r16]; packed u32 stores
  int nrow = n0 + (s << 4) + r16;
  u16* orow = attout + ((size_t)bb * 8192 + nrow) * 512 + h * 64;
  #pragma unroll
  for (int dvt = 0; dvt < 4; dvt++) {
    #pragma unroll
    for (int pr = 0; pr < 2; pr++) {
      u32 wv = cvtpk(o[dvt][2 * pr] * inv, o[dvt][2 * pr + 1] * inv);
      *(u32*)(orow + (dvt << 4) + (g << 2) + (pr << 1)) = wv;
    }
  }
}

// ---------------- output GEMM: [32768,512]bf16 @ [512,512]bf16^T + bias -> f32 ---------
__global__ __launch_bounds__(256) void k_gemm_out(const u16* __restrict__ Aq,
                                                  const u16* __restrict__ Bq,
                                                  const float* __restrict__ bias,
                                                  float* __restrict__ out) {
  __shared__ u16 As[128 * 32];
  __shared__ u16 Bs[128 * 32];
  int tid = threadIdx.x;
  int bid = blockIdx.x;
  int swz = (bid & 7) * (gridDim.x >> 3) + (bid >> 3);   // 1024 % 8 == 0
  int m0 = (swz >> 2) * 128, n0 = (swz & 3) * 128;
  int wid = tid >> 6, lane = tid & 63, g = lane >> 4, r16 = lane & 15;
  int wm = wid >> 1, wn = wid & 1;
  f32x4 acc[4][4];
  #pragma unroll
  for (int i = 0; i < 4; i++)
    #pragma unroll
    for (int j = 0; j < 4; j++) acc[i][j] = (f32x4){0.f, 0.f, 0.f, 0.f};
  const u16* Ab = Aq + (size_t)m0 * 512;
  const u16* Bb = Bq + (size_t)n0 * 512;
  char* AsB = (char*)As + wid * 1024;
  char* BsB = (char*)Bs + wid * 1024;
  int srow = tid >> 2;
  int scol = ((tid & 3) ^ ((tid >> 3) & 3)) * 8;
  int gs = (g ^ ((r16 >> 1) & 3)) * 8;
  for (int k0 = 0; k0 < 512; k0 += 32) {
    __syncthreads();
    GLL(Ab + (size_t)srow * 512 + k0 + scol, AsB);
    GLL(Ab + (size_t)(srow + 64) * 512 + k0 + scol, AsB + 4096);
    GLL(Bb + (size_t)srow * 512 + k0 + scol, BsB);
    GLL(Bb + (size_t)(srow + 64) * 512 + k0 + scol, BsB + 4096);
    __syncthreads();
    bf16x8 a[4], b[4];
    #pragma unroll
    for (int mt = 0; mt < 4; mt++)
      a[mt] = *(const bf16x8*)(As + (wm * 64 + mt * 16 + r16) * 32 + gs);
    #pragma unroll
    for (int nt = 0; nt < 4; nt++)
      b[nt] = *(const bf16x8*)(Bs + (wn * 64 + nt * 16 + r16) * 32 + gs);
    #pragma unroll
    for (int mt = 0; mt < 4; mt++)
      #pragma unroll
      for (int nt = 0; nt < 4; nt++) acc[mt][nt] = mfma16(a[mt], b[nt], acc[mt][nt]);
  }
  #pragma unroll
  for (int nt = 0; nt < 4; nt++) {
    int col = n0 + wn * 64 + nt * 16 + r16;
    float bv = bias[col];
    #pragma unroll
    for (int mt = 0; mt < 4; mt++) {
      int mbase = m0 + wm * 64 + mt * 16 + 4 * g;
      #pragma unroll
      for (int rr = 0; rr < 4; rr++) {
        int m = mbase + rr;
        out[(size_t)m * 512 + col] = acc[mt][nt][rr] + bv;
      }
    }
  }
}

extern "C" void kernel_launch(void* const* d_in, const int* in_sizes, int n_in,
                              void* d_out, int out_size, void* d_ws, size_t ws_size,
                              hipStream_t stream) {
  const float* x     = (const float*)d_in[0];
  const float* w_qkv = (const float*)d_in[1];
  const float* w_out = (const float*)d_in[2];
  const float* b_out = (const float*)d_in[3];
  const float* w_rel = (const float*)d_in[4];
  const float* cb    = (const float*)d_in[5];   // rel_content_bias [1,8,1,1,64]
  const float* pb    = (const float*)d_in[6];   // rel_pos_bias
  float* out = (float*)d_out;

  char* p = (char*)d_ws;
  u16* xq   = (u16*)p; p += (size_t)32768 * 512 * 2;       // 32 MB
  u16* wq   = (u16*)p; p += (size_t)1536 * 512 * 2;        // 1.5 MB (rows permuted: comp,h,d)
  u16* wo   = (u16*)p; p += (size_t)512 * 512 * 2;         // 0.5 MB
  u16* relk = (u16*)p; p += (size_t)8 * 256 * 64 * 2;      // 256 KB
  float* pbR = (float*)p; p += (size_t)8 * 256 * 4;        // 8 KB
  u16* Qb   = (u16*)p; p += (size_t)4 * 8 * 8192 * 64 * 2; // 32 MB
  u16* Kb   = (u16*)p; p += (size_t)4 * 8 * 8192 * 64 * 2;
  u16* Vb   = (u16*)p; p += (size_t)4 * 8 * 8192 * 64 * 2;
  u16* att  = (u16*)p; p += (size_t)32768 * 512 * 2;       // 32 MB

  hipLaunchKernelGGL(k_quant, dim3(2048), dim3(256), 0, stream, x, w_qkv, w_out, xq, wq, wo);
  hipLaunchKernelGGL(k_relk, dim3(256, 4), dim3(128), 0, stream, w_rel, pb, relk, pbR);
  hipLaunchKernelGGL(k_gemm_qkv, dim3(3072), dim3(256), 0, stream, xq, wq, Qb, Kb, Vb);
  hipLaunchKernelGGL(k_attn, dim3(2048), dim3(512), 0, stream, Qb, Kb, Vb, relk, pbR, cb, att);
  hipLaunchKernelGGL(k_gemm_out, dim3(1024), dim3(256), 0, stream, att, wo, b_out, out);
}

// Round 9
// 357.033 us; speedup vs baseline: 1.2336x; 1.2336x over previous
//
#include <hip/hip_runtime.h>

typedef unsigned short u16;
typedef unsigned int u32;
typedef __attribute__((ext_vector_type(8))) __bf16 bf16x8;
typedef __attribute__((ext_vector_type(4))) float f32x4;
typedef __attribute__((ext_vector_type(8))) unsigned short u16x8;
typedef __attribute__((ext_vector_type(4))) unsigned short u16x4;
typedef __attribute__((ext_vector_type(4))) unsigned int u32x4;

#define GLL(gp, lp) __builtin_amdgcn_global_load_lds((const __attribute__((address_space(1))) void*)(gp), (__attribute__((address_space(3))) void*)(lp), 16, 0, 0)

__device__ __forceinline__ u16 f2bf(float f) {
  u32 u = __float_as_uint(f);
  u += 0x7FFFu + ((u >> 16) & 1u);   // RNE; no NaNs in this pipeline
  return (u16)(u >> 16);
}
__device__ __forceinline__ float bf2f(u16 u) { return __uint_as_float(((u32)u) << 16); }
__device__ __forceinline__ u32 cvtpk(float lo, float hi) {  // D[15:0]=bf16(lo), D[31:16]=bf16(hi)
  u32 r;
  asm("v_cvt_pk_bf16_f32 %0, %1, %2" : "=v"(r) : "v"(lo), "v"(hi));
  return r;
}
__device__ __forceinline__ float qz(float v) {  // MASE integer_quantizer fwd, width=8 frac=4
  float r = rintf(v * 16.0f);
  r = fminf(127.0f, fmaxf(-128.0f, r));
  return r * 0.0625f;
}
__device__ __forceinline__ f32x4 mfma16(bf16x8 a, bf16x8 b, f32x4 c) {
  return __builtin_amdgcn_mfma_f32_16x16x32_bf16(a, b, c, 0, 0, 0);
}

// ---------------- quantize x, w_qkv, w_out -> bf16 (exact representations) -------------
// w_qkv rows are PERMUTED on store: src row h*192+d*3+comp -> dst row comp*512+h*64+d.
__global__ __launch_bounds__(256) void k_quant(const float* __restrict__ x,
                                               const float* __restrict__ wqkv,
                                               const float* __restrict__ wout,
                                               u16* __restrict__ xq,
                                               u16* __restrict__ wq,
                                               u16* __restrict__ wo) {
  const int X4 = 4194304;   // 4*8192*512 /4
  const int W4 = 196608;    // 1536*512 /4
  const int O4 = 65536;     // 512*512 /4
  int stride = gridDim.x * blockDim.x;
  for (int i = blockIdx.x * blockDim.x + threadIdx.x; i < X4 + W4 + O4; i += stride) {
    const float4* s; u16* d; int jl, jd;
    if (i < X4) {
      s = (const float4*)x; d = xq; jl = i; jd = i;
    } else if (i < X4 + W4) {
      s = (const float4*)wqkv; d = wq;
      jl = i - X4;
      int rs = jl >> 7;            // source row (128 float4 per 512-elem row)
      int jc = jl & 127;
      int h = rs / 192;
      int rem = rs - h * 192;
      int dd = rem / 3;
      int comp = rem - dd * 3;
      jd = (comp * 512 + h * 64 + dd) * 128 + jc;
    } else {
      s = (const float4*)wout; d = wo; jl = i - X4 - W4; jd = jl;
    }
    float4 v = s[jl];
    u16x4 o;
    o.x = f2bf(qz(v.x)); o.y = f2bf(qz(v.y)); o.z = f2bf(qz(v.z)); o.w = f2bf(qz(v.w));
    *(u16x4*)(d + (size_t)jd * 4) = o;
  }
}

// ---------------- rel_k = positions @ w_rel.T  -> bf16 [8][256][64];  pbR[h][256] ------
__global__ __launch_bounds__(128) void k_relk(const float* __restrict__ w_rel,
                                              const float* __restrict__ pb,   // [512]
                                              u16* __restrict__ relk,         // [8][256][64]
                                              float* __restrict__ pbR) {      // [8][256]
  int r = blockIdx.x;        // 0..255 (position index; d = r-127)
  int cseg = blockIdx.y;     // 0..3
  int tid = threadIdx.x;     // 0..127
  int c = cseg * 128 + tid;  // output channel 0..511: h = c>>6, d = c&63
  if (r == 255) {            // padding row: zero (read by MFMA A-frags, never selected)
    relk[((size_t)(c >> 6) * 256 + 255) * 64 + (c & 63)] = 0;
    if ((tid & 63) == 0) pbR[(c >> 6) * 256 + 255] = 0.f;
    return;
  }
  __shared__ float pos[512];
  float dd = (float)(r - 127);
  float ad = fabsf(dd);
  float sg = (dd > 0.f) ? 1.f : ((dd < 0.f) ? -1.f : 0.f);
  for (int f = tid; f < 512; f += 128) {
    int base = f & 255;
    float feat;
    if (base < 128) {  // exponential features: half_life = 2^linspace(3, 7, 128)
      float hl = exp2f(3.0f + (float)base * (4.0f / 127.0f));
      feat = expf((-0.6931471805599453f / hl) * ad);
    } else {           // central-mask features: 2^(j+1)-1 > |d|  (2^128 -> inf, matches ref)
      float cw = exp2f((float)(base - 128 + 1)) - 1.0f;
      feat = (cw > ad) ? 1.0f : 0.0f;
    }
    if (f >= 256) feat *= sg;
    pos[f] = feat;
  }
  __syncthreads();
  const float4* wr4 = (const float4*)(w_rel + (size_t)c * 512);
  float acc = 0.f;
  #pragma unroll 4
  for (int f4 = 0; f4 < 128; f4++) {
    float4 w4 = wr4[f4];
    int f = f4 * 4;
    acc += pos[f] * w4.x + pos[f + 1] * w4.y + pos[f + 2] * w4.z + pos[f + 3] * w4.w;
  }
  relk[((size_t)(c >> 6) * 256 + r) * 64 + (c & 63)] = f2bf(acc);
  float contrib = acc * pb[c];
  #pragma unroll
  for (int off = 1; off < 64; off <<= 1) contrib += __shfl_xor(contrib, off, 64);
  if ((tid & 63) == 0) pbR[(c >> 6) * 256 + r] = contrib;
}

// ---------------- QKV GEMM: [32768,512]bf16 @ [1536,512]bf16^T(permuted rows) ----------
__global__ __launch_bounds__(256) void k_gemm_qkv(const u16* __restrict__ Aq,
                                                  const u16* __restrict__ Bq,
                                                  u16* __restrict__ Qo,
                                                  u16* __restrict__ Ko,
                                                  u16* __restrict__ Vo) {
  __shared__ u16 As[128 * 32];
  __shared__ u16 Bs[128 * 32];
  int tid = threadIdx.x;
  int bid = blockIdx.x;
  int swz = (bid & 7) * (gridDim.x >> 3) + (bid >> 3);   // XCD swizzle (3072 % 8 == 0)
  int m0 = (swz / 12) * 128, n0 = (swz % 12) * 128;
  int wid = tid >> 6, lane = tid & 63, g = lane >> 4, r16 = lane & 15;
  int wm = wid >> 1, wn = wid & 1;
  f32x4 acc[4][4];
  #pragma unroll
  for (int i = 0; i < 4; i++)
    #pragma unroll
    for (int j = 0; j < 4; j++) acc[i][j] = (f32x4){0.f, 0.f, 0.f, 0.f};
  const u16* Ab = Aq + (size_t)m0 * 512;
  const u16* Bb = Bq + (size_t)n0 * 512;
  char* AsB = (char*)As + wid * 1024;
  char* BsB = (char*)Bs + wid * 1024;
  int srow = tid >> 2;
  int scol = ((tid & 3) ^ ((tid >> 3) & 3)) * 8;   // pre-swizzled source chunk
  int gs = (g ^ ((r16 >> 1) & 3)) * 8;             // swizzled read chunk
  for (int k0 = 0; k0 < 512; k0 += 32) {
    __syncthreads();
    GLL(Ab + (size_t)srow * 512 + k0 + scol, AsB);
    GLL(Ab + (size_t)(srow + 64) * 512 + k0 + scol, AsB + 4096);
    GLL(Bb + (size_t)srow * 512 + k0 + scol, BsB);
    GLL(Bb + (size_t)(srow + 64) * 512 + k0 + scol, BsB + 4096);
    __syncthreads();
    bf16x8 a[4], b[4];
    #pragma unroll
    for (int mt = 0; mt < 4; mt++)
      a[mt] = *(const bf16x8*)(As + (wm * 64 + mt * 16 + r16) * 32 + gs);
    #pragma unroll
    for (int nt = 0; nt < 4; nt++)
      b[nt] = *(const bf16x8*)(Bs + (wn * 64 + nt * 16 + r16) * 32 + gs);
    #pragma unroll
    for (int mt = 0; mt < 4; mt++)
      #pragma unroll
      for (int nt = 0; nt < 4; nt++) acc[mt][nt] = mfma16(a[mt], b[nt], acc[mt][nt]);
  }
  // epilogue: col -> (comp | h*64+d); store [b][h][n][64] bf16, 32B-coalesced runs
  #pragma unroll
  for (int nt = 0; nt < 4; nt++) {
    int colc = n0 + wn * 64 + nt * 16 + r16;
    int comp = colc >> 9;
    int hd = colc & 511;
    u16* dst = (comp == 0) ? Qo : (comp == 1 ? Ko : Vo);
    u16* dstp = dst + (size_t)(hd >> 6) * 524288 + (hd & 63);
    #pragma unroll
    for (int mt = 0; mt < 4; mt++) {
      int mbase = m0 + wm * 64 + mt * 16 + 4 * g;
      #pragma unroll
      for (int rr = 0; rr < 4; rr++) {
        int m = mbase + rr;
        int bb = m >> 13, nn = m & 8191;
        dstp[(size_t)bb * 4194304 + (size_t)nn * 64] = f2bf(acc[mt][nt][rr]);
      }
    }
  }
}

// ---------------- windowed attention (swapped-operand, Pst-free) -----------------------
// S^T layout: lane(g,r16) holds S[q=s*16+r16][k=kt*16+4g+rr]; softmax per-lane + 2 shfl;
// P redistributed to PV B-frags via in-register shuffles (no LDS P buffer).
__device__ __forceinline__ f32x4 rel_tile(const u16* __restrict__ Rh,
                                          const float* __restrict__ pbRh,
                                          bf16x8 qb0, bf16x8 qb1,
                                          int ct, int r16, int g) {
  const u16* rp = Rh + ((ct << 4) + r16) * 64 + (g << 3);
  bf16x8 rb0 = *(const bf16x8*)rp;
  bf16x8 rb1 = *(const bf16x8*)(rp + 32);
  f32x4 c = {0.f, 0.f, 0.f, 0.f};
  c = mfma16(rb0, qb0, c);
  c = mfma16(rb1, qb1, c);
  f32x4 pv = *(const f32x4*)(pbRh + (ct << 4) + (g << 2));
  c[0] += pv[0]; c[1] += pv[1]; c[2] += pv[2]; c[3] += pv[3];
  return c;
}

__global__ __launch_bounds__(512, 4) void k_attn(const u16* __restrict__ Q,
                                                 const u16* __restrict__ K,
                                                 const u16* __restrict__ V,
                                                 const u16* __restrict__ relk,
                                                 const float* __restrict__ pbR,
                                                 const float* __restrict__ cb,   // [512]
                                                 u16* __restrict__ attout) {
  int bid = blockIdx.x;            // 2048 = 4*8*64
  int bb = bid >> 9;
  int h = (bid >> 6) & 7;
  int w = bid & 63;
  int tid = threadIdx.x;
  int s = tid >> 6;                // wave id == q-stripe (16 rows)
  int lane = tid & 63, g = lane >> 4, r16 = lane & 15;
  const int n0 = w * 128;
  const u16* Qh = Q + ((size_t)(bb * 8 + h) * 8192 + n0) * 64;
  const u16* Kh = K + ((size_t)(bb * 8 + h) * 8192 + n0) * 64;
  const u16* Vh = V + ((size_t)(bb * 8 + h) * 8192 + n0) * 64;
  const u16* Rh = relk + (size_t)h * 256 * 64;
  const float* pbRh = pbR + h * 256;

  __shared__ u16 VT[64 * 128];      // V^T: key-chunk XOR-swizzled: chunk ^= (dv^(dv>>3))&7
  __shared__ float cbK[128];        // content-bias dot key

  // --- stage V transposed: 512 threads, each packs a key-PAIR for 8 dv (u32 writes, ~2-way)
  {
    int r2 = tid >> 3;               // key pair index 0..63 -> keys 2r2, 2r2+1
    int c0 = (tid & 7) << 3;         // dv base
    const u16* src = Vh + r2 * 128 + c0;
    u16x8 v0 = *(const u16x8*)src;
    u16x8 v1 = *(const u16x8*)(src + 64);
    int kc = r2 >> 2;                // key chunk (8 keys)
    int pos = (r2 & 3) << 1;         // position of key pair within chunk
    #pragma unroll
    for (int j = 0; j < 8; j++) {
      int dv = c0 + j;
      int swzv = (dv ^ (dv >> 3)) & 7;
      u32 wv = (u32)v0[j] | ((u32)v1[j] << 16);
      *(u32*)(VT + dv * 128 + ((kc ^ swzv) << 3) + pos) = wv;
    }
  }
  // --- cbK[k] = sum_d cb[h][d] * K[k][d] (f32; folds rel_content_bias exactly)
  if (tid < 128) {
    const u16x8* kr8 = (const u16x8*)(Kh + tid * 64);
    const float* cbh = cb + h * 64;
    float a = 0.f;
    #pragma unroll
    for (int d8 = 0; d8 < 8; d8++) {
      u16x8 kv = kr8[d8];
      #pragma unroll
      for (int j = 0; j < 8; j++) a += cbh[d8 * 8 + j] * bf2f(kv[j]);
    }
    cbK[tid] = a;
  }

  // --- Q fragments (B-operand: col = q = s*16 + r16)
  const u16* qptr = Qh + ((s << 4) + r16) * 64 + (g << 3);
  bf16x8 qb0 = *(const bf16x8*)qptr;
  bf16x8 qb1 = *(const bf16x8*)(qptr + 32);

  // --- content scores S[q][k] (swapped): sc[kt][rr] = S[q=r16][k=kt*16+4g+rr]
  f32x4 sc[8];
  #pragma unroll
  for (int kt = 0; kt < 8; kt++) {
    const u16* kp = Kh + ((kt << 4) + r16) * 64 + (g << 3);
    bf16x8 kf0 = *(const bf16x8*)kp;
    bf16x8 kf1 = *(const bf16x8*)(kp + 32);
    f32x4 c = {0.f, 0.f, 0.f, 0.f};
    c = mfma16(kf0, qb0, c);
    sc[kt] = mfma16(kf1, qb1, c);
  }

  // --- rel band + shift-gather. rl tile t holds RL[q=r16][c=ct*16+4g+rr], ct=7-s+t.
  // pos[q][k] = RL[q][127+k-q]: loc = 15+4g+rr-r16; tile kt (loc<16) or kt+1; cl=loc&15.
  int a0 = (3 - r16) & 3;            // per-lane register rotation amount
  bool rb0s = (a0 & 1) != 0, rb1s = (a0 & 2) != 0;
  float rotA[4], rotB[4];
  {
    f32x4 rl = rel_tile(Rh, pbRh, qb0, qb1, 7 - s, r16, g);
    float s1[4];
    #pragma unroll
    for (int i = 0; i < 4; i++) s1[i] = rb0s ? rl[(i + 1) & 3] : rl[i];
    #pragma unroll
    for (int i = 0; i < 4; i++) rotA[i] = rb1s ? s1[(i + 2) & 3] : s1[i];
  }
  // per-rr gather constants (independent of kt)
  int srcl[4]; bool hisel[4];
  #pragma unroll
  for (int rr = 0; rr < 4; rr++) {
    int loc = 15 + 4 * g + rr - r16;
    srcl[rr] = (((loc & 15) >> 2) << 4) | r16;
    hisel[rr] = loc >= 16;
  }

  __syncthreads();   // VT + cbK ready (also fences before cbK reads below)

  #pragma unroll
  for (int kt = 0; kt < 8; kt++) {
    f32x4 rl = rel_tile(Rh, pbRh, qb0, qb1, 8 - s + kt, r16, g);
    float s1[4];
    #pragma unroll
    for (int i = 0; i < 4; i++) s1[i] = rb0s ? rl[(i + 1) & 3] : rl[i];
    #pragma unroll
    for (int i = 0; i < 4; i++) rotB[i] = rb1s ? s1[(i + 2) & 3] : s1[i];
    f32x4 cbv = *(const f32x4*)(&cbK[(kt << 4) + (g << 2)]);
    #pragma unroll
    for (int rr = 0; rr < 4; rr++) {
      float vlo = __shfl(rotA[rr], srcl[rr], 64);
      float vhi = __shfl(rotB[rr], srcl[rr], 64);
      float posv = hisel[rr] ? vhi : vlo;
      sc[kt][rr] = (sc[kt][rr] + cbv[rr]) * 0.125f + posv;
    }
    #pragma unroll
    for (int i = 0; i < 4; i++) rotA[i] = rotB[i];
  }

  // --- softmax over k: per-lane 32 values + 2-step cross-lane (xor 16, 32)
  float mx = sc[0][0];
  #pragma unroll
  for (int kt = 0; kt < 8; kt++)
    #pragma unroll
    for (int rr = 0; rr < 4; rr++) mx = fmaxf(mx, sc[kt][rr]);
  mx = fmaxf(mx, __shfl_xor(mx, 16, 64));
  mx = fmaxf(mx, __shfl_xor(mx, 32, 64));
  float sum = 0.f;
  #pragma unroll
  for (int kt = 0; kt < 8; kt++)
    #pragma unroll
    for (int rr = 0; rr < 4; rr++) {
      float p = expf(sc[kt][rr] - mx);
      sc[kt][rr] = p;
      sum += p;
    }
  sum += __shfl_xor(sum, 16, 64);
  sum += __shfl_xor(sum, 32, 64);
  float inv = 1.0f / sum;

  // --- PV: O^T[dv][q] — B-frag built via 4-lane-group shuffles (static reg indices);
  //     P packed to bf16 inline (pkb not kept live across the whole loop).
  f32x4 o[4];
  #pragma unroll
  for (int dvt = 0; dvt < 4; dvt++) o[dvt] = (f32x4){0.f, 0.f, 0.f, 0.f};
  int L0 = ((g & 1) << 5) | r16;
  int L1 = L0 + 16;
  bool ghi = g >= 2;
  #pragma unroll
  for (int ks = 0; ks < 4; ks++) {
    int e = 2 * ks;
    u32 pe0 = cvtpk(sc[e][0], sc[e][1]);
    u32 pe1 = cvtpk(sc[e][2], sc[e][3]);
    u32 pf0 = cvtpk(sc[e + 1][0], sc[e + 1][1]);
    u32 pf1 = cvtpk(sc[e + 1][2], sc[e + 1][3]);
    u32 w0a = __shfl((int)pe0, L0, 64), w0b = __shfl((int)pf0, L0, 64);
    u32 w1a = __shfl((int)pe1, L0, 64), w1b = __shfl((int)pf1, L0, 64);
    u32 w2a = __shfl((int)pe0, L1, 64), w2b = __shfl((int)pf0, L1, 64);
    u32 w3a = __shfl((int)pe1, L1, 64), w3b = __shfl((int)pf1, L1, 64);
    u32x4 wv;
    wv.x = ghi ? w0b : w0a;
    wv.y = ghi ? w1b : w1a;
    wv.z = ghi ? w2b : w2a;
    wv.w = ghi ? w3b : w3a;
    bf16x8 pf = __builtin_bit_cast(bf16x8, wv);
    #pragma unroll
    for (int dvt = 0; dvt < 4; dvt++) {
      int dv = (dvt << 4) | r16;
      int swzv = (dv ^ (dv >> 3)) & 7;
      bf16x8 vf = *(const bf16x8*)(VT + dv * 128 + (((ks * 4 + g) ^ swzv) << 3));
      o[dvt] = mfma16(vf, pf, o[dvt]);
    }
  }

  // --- epilogue: lane holds O[dv=dvt*16+4g+rr][q=r16]; packed u32 stores
  int nrow = n0 + (s << 4) + r16;
  u16* orow = attout + ((size_t)bb * 8192 + nrow) * 512 + h * 64;
  #pragma unroll
  for (int dvt = 0; dvt < 4; dvt++) {
    #pragma unroll
    for (int pr = 0; pr < 2; pr++) {
      u32 wv = cvtpk(o[dvt][2 * pr] * inv, o[dvt][2 * pr + 1] * inv);
      *(u32*)(orow + (dvt << 4) + (g << 2) + (pr << 1)) = wv;
    }
  }
}

// ---------------- output GEMM: [32768,512]bf16 @ [512,512]bf16^T + bias -> f32 ---------
__global__ __launch_bounds__(256) void k_gemm_out(const u16* __restrict__ Aq,
                                                  const u16* __restrict__ Bq,
                                                  const float* __restrict__ bias,
                                                  float* __restrict__ out) {
  __shared__ u16 As[128 * 32];
  __shared__ u16 Bs[128 * 32];
  int tid = threadIdx.x;
  int bid = blockIdx.x;
  int swz = (bid & 7) * (gridDim.x >> 3) + (bid >> 3);   // 1024 % 8 == 0
  int m0 = (swz >> 2) * 128, n0 = (swz & 3) * 128;
  int wid = tid >> 6, lane = tid & 63, g = lane >> 4, r16 = lane & 15;
  int wm = wid >> 1, wn = wid & 1;
  f32x4 acc[4][4];
  #pragma unroll
  for (int i = 0; i < 4; i++)
    #pragma unroll
    for (int j = 0; j < 4; j++) acc[i][j] = (f32x4){0.f, 0.f, 0.f, 0.f};
  const u16* Ab = Aq + (size_t)m0 * 512;
  const u16* Bb = Bq + (size_t)n0 * 512;
  char* AsB = (char*)As + wid * 1024;
  char* BsB = (char*)Bs + wid * 1024;
  int srow = tid >> 2;
  int scol = ((tid & 3) ^ ((tid >> 3) & 3)) * 8;
  int gs = (g ^ ((r16 >> 1) & 3)) * 8;
  for (int k0 = 0; k0 < 512; k0 += 32) {
    __syncthreads();
    GLL(Ab + (size_t)srow * 512 + k0 + scol, AsB);
    GLL(Ab + (size_t)(srow + 64) * 512 + k0 + scol, AsB + 4096);
    GLL(Bb + (size_t)srow * 512 + k0 + scol, BsB);
    GLL(Bb + (size_t)(srow + 64) * 512 + k0 + scol, BsB + 4096);
    __syncthreads();
    bf16x8 a[4], b[4];
    #pragma unroll
    for (int mt = 0; mt < 4; mt++)
      a[mt] = *(const bf16x8*)(As + (wm * 64 + mt * 16 + r16) * 32 + gs);
    #pragma unroll
    for (int nt = 0; nt < 4; nt++)
      b[nt] = *(const bf16x8*)(Bs + (wn * 64 + nt * 16 + r16) * 32 + gs);
    #pragma unroll
    for (int mt = 0; mt < 4; mt++)
      #pragma unroll
      for (int nt = 0; nt < 4; nt++) acc[mt][nt] = mfma16(a[mt], b[nt], acc[mt][nt]);
  }
  #pragma unroll
  for (int nt = 0; nt < 4; nt++) {
    int col = n0 + wn * 64 + nt * 16 + r16;
    float bv = bias[col];
    #pragma unroll
    for (int mt = 0; mt < 4; mt++) {
      int mbase = m0 + wm * 64 + mt * 16 + 4 * g;
      #pragma unroll
      for (int rr = 0; rr < 4; rr++) {
        int m = mbase + rr;
        out[(size_t)m * 512 + col] = acc[mt][nt][rr] + bv;
      }
    }
  }
}

extern "C" void kernel_launch(void* const* d_in, const int* in_sizes, int n_in,
                              void* d_out, int out_size, void* d_ws, size_t ws_size,
                              hipStream_t stream) {
  const float* x     = (const float*)d_in[0];
  const float* w_qkv = (const float*)d_in[1];
  const float* w_out = (const float*)d_in[2];
  const float* b_out = (const float*)d_in[3];
  const float* w_rel = (const float*)d_in[4];
  const float* cb    = (const float*)d_in[5];   // rel_content_bias [1,8,1,1,64]
  const float* pb    = (const float*)d_in[6];   // rel_pos_bias
  float* out = (float*)d_out;

  char* p = (char*)d_ws;
  u16* xq   = (u16*)p; p += (size_t)32768 * 512 * 2;       // 32 MB
  u16* wq   = (u16*)p; p += (size_t)1536 * 512 * 2;        // 1.5 MB (rows permuted: comp,h,d)
  u16* wo   = (u16*)p; p += (size_t)512 * 512 * 2;         // 0.5 MB
  u16* relk = (u16*)p; p += (size_t)8 * 256 * 64 * 2;      // 256 KB
  float* pbR = (float*)p; p += (size_t)8 * 256 * 4;        // 8 KB
  u16* Qb   = (u16*)p; p += (size_t)4 * 8 * 8192 * 64 * 2; // 32 MB
  u16* Kb   = (u16*)p; p += (size_t)4 * 8 * 8192 * 64 * 2;
  u16* Vb   = (u16*)p; p += (size_t)4 * 8 * 8192 * 64 * 2;
  u16* att  = (u16*)p; p += (size_t)32768 * 512 * 2;       // 32 MB

  hipLaunchKernelGGL(k_quant, dim3(2048), dim3(256), 0, stream, x, w_qkv, w_out, xq, wq, wo);
  hipLaunchKernelGGL(k_relk, dim3(256, 4), dim3(128), 0, stream, w_rel, pb, relk, pbR);
  hipLaunchKernelGGL(k_gemm_qkv, dim3(3072), dim3(256), 0, stream, xq, wq, Qb, Kb, Vb);
  hipLaunchKernelGGL(k_attn, dim3(2048), dim3(512), 0, stream, Qb, Kb, Vb, relk, pbR, cb, att);
  hipLaunchKernelGGL(k_gemm_out, dim3(1024), dim3(256), 0, stream, att, wo, b_out, out);
}